// Round 1
// baseline (1385.701 us; speedup 1.0000x reference)
//
#include <hip/hip_runtime.h>
#include <math.h>

// Decoder (temporal cross-attn) — fp32 baseline, last-layer-only.
// Dims fixed by the reference.
constexpr int SEQL = 128;
constexpr int NH   = 8;
constexpr int EMB  = 256;
constexpr int NB   = 64;
constexpr int CCH  = SEQL * NH;          // 1024 channels
constexpr int ROWSTR = NH * EMB;         // 2048 floats between consecutive s for fixed head
constexpr size_t SZ = (size_t)NB * CCH * EMB;  // 16,777,216 floats per activation tensor

// ---------------------------------------------------------------------------
// G1: out[M,256] = A[M,256] @ W[256,256] + bias  (+res) (+leaky_relu)
// 64x64 tile, 256 threads, 4x4 per thread, K-chunks of 16.
// ---------------------------------------------------------------------------
template<int ACT, int RES>
__global__ __launch_bounds__(256)
void gemm256(const float* __restrict__ A, const float* __restrict__ W,
             const float* __restrict__ bias, const float* __restrict__ res,
             float* __restrict__ out)
{
    __shared__ float As[16 * 64];   // [k][m] (transposed stage)
    __shared__ float Bs[16 * 64];   // [k][n]
    const int tid    = threadIdx.x;
    const int tile_n = blockIdx.x & 3;
    const int tile_m = blockIdx.x >> 2;
    const int m0 = tile_m * 64, n0 = tile_n * 64;
    const int tm = tid & 15, tn = tid >> 4;
    const int lm = tid >> 2, lc = tid & 3;     // A staging: row, e-chunk
    const int bk = tid >> 4, bn = tid & 15;    // B staging: k-row, n-chunk

    float acc[4][4] = {};
    for (int kt = 0; kt < 16; ++kt) {
        __syncthreads();
        float4 av = *(const float4*)(A + (size_t)(m0 + lm) * EMB + kt * 16 + lc * 4);
        As[(lc*4+0)*64 + lm] = av.x;
        As[(lc*4+1)*64 + lm] = av.y;
        As[(lc*4+2)*64 + lm] = av.z;
        As[(lc*4+3)*64 + lm] = av.w;
        float4 wv = *(const float4*)(W + (size_t)(kt*16 + bk) * EMB + n0 + bn * 4);
        *(float4*)(Bs + bk*64 + bn*4) = wv;
        __syncthreads();
        #pragma unroll
        for (int kk = 0; kk < 16; ++kk) {
            float4 a = *(const float4*)(As + kk*64 + tm*4);
            float4 b = *(const float4*)(Bs + kk*64 + tn*4);
            acc[0][0] += a.x*b.x; acc[0][1] += a.x*b.y; acc[0][2] += a.x*b.z; acc[0][3] += a.x*b.w;
            acc[1][0] += a.y*b.x; acc[1][1] += a.y*b.y; acc[1][2] += a.y*b.z; acc[1][3] += a.y*b.w;
            acc[2][0] += a.z*b.x; acc[2][1] += a.z*b.y; acc[2][2] += a.z*b.z; acc[2][3] += a.z*b.w;
            acc[3][0] += a.w*b.x; acc[3][1] += a.w*b.y; acc[3][2] += a.w*b.z; acc[3][3] += a.w*b.w;
        }
    }
    float4 bb = *(const float4*)(bias + n0 + tn*4);
    #pragma unroll
    for (int i = 0; i < 4; ++i) {
        const size_t row = (size_t)(m0 + tm*4 + i);
        float4 o;
        o.x = acc[i][0] + bb.x; o.y = acc[i][1] + bb.y;
        o.z = acc[i][2] + bb.z; o.w = acc[i][3] + bb.w;
        if (RES) {
            float4 r = *(const float4*)(res + row*EMB + n0 + tn*4);
            o.x += r.x; o.y += r.y; o.z += r.z; o.w += r.w;
        }
        if (ACT) {
            o.x = o.x > 0.f ? o.x : 0.01f*o.x;
            o.y = o.y > 0.f ? o.y : 0.01f*o.y;
            o.z = o.z > 0.f ? o.z : 0.01f*o.z;
            o.w = o.w > 0.f ? o.w : 0.01f*o.w;
        }
        *(float4*)(out + row*EMB + n0 + tn*4) = o;
    }
}

// ---------------------------------------------------------------------------
// Attention helpers.
// qkgemm_phase: scores[64 x 128] = Arows[64 x 256] · Brows[128 x 256]^T
// (dot over e). Writes into LDS `qk` with stride 129 (conflict-free columns).
// ---------------------------------------------------------------------------
__device__ __forceinline__ void qkgemm_phase(float* __restrict__ qk,
                                             float* __restrict__ As, float* __restrict__ Bs,
                                             const float* __restrict__ Arows, size_t astride,
                                             const float* __restrict__ Brows, size_t bstride,
                                             int tid)
{
    const int tm = tid & 15, tn = tid >> 4;
    const int lm = tid >> 2, lc = tid & 3;
    for (int lt = 0; lt < 2; ++lt) {
        float acc[4][4] = {};
        for (int et = 0; et < 16; ++et) {
            __syncthreads();
            float4 av = *(const float4*)(Arows + (size_t)lm * astride + et*16 + lc*4);
            As[(lc*4+0)*64 + lm] = av.x;
            As[(lc*4+1)*64 + lm] = av.y;
            As[(lc*4+2)*64 + lm] = av.z;
            As[(lc*4+3)*64 + lm] = av.w;
            float4 bv = *(const float4*)(Brows + (size_t)(lt*64 + lm) * bstride + et*16 + lc*4);
            Bs[(lc*4+0)*64 + lm] = bv.x;
            Bs[(lc*4+1)*64 + lm] = bv.y;
            Bs[(lc*4+2)*64 + lm] = bv.z;
            Bs[(lc*4+3)*64 + lm] = bv.w;
            __syncthreads();
            #pragma unroll
            for (int kk = 0; kk < 16; ++kk) {
                float4 a = *(const float4*)(As + kk*64 + tm*4);
                float4 b = *(const float4*)(Bs + kk*64 + tn*4);
                acc[0][0] += a.x*b.x; acc[0][1] += a.x*b.y; acc[0][2] += a.x*b.z; acc[0][3] += a.x*b.w;
                acc[1][0] += a.y*b.x; acc[1][1] += a.y*b.y; acc[1][2] += a.y*b.z; acc[1][3] += a.y*b.w;
                acc[2][0] += a.z*b.x; acc[2][1] += a.z*b.y; acc[2][2] += a.z*b.z; acc[2][3] += a.z*b.w;
                acc[3][0] += a.w*b.x; acc[3][1] += a.w*b.y; acc[3][2] += a.w*b.z; acc[3][3] += a.w*b.w;
            }
        }
        #pragma unroll
        for (int i = 0; i < 4; ++i)
            #pragma unroll
            for (int j = 0; j < 4; ++j)
                qk[(tm*4 + i)*129 + lt*64 + tn*4 + j] = acc[i][j];
    }
}

// zgemm_phase: Z[q0+0..63, e] (+)= scores[64 x 128] · Vrows[128 x 256]
__device__ __forceinline__ void zgemm_phase(const float* __restrict__ qk,
                                            float* __restrict__ Bs,
                                            const float* __restrict__ V,
                                            float* __restrict__ Z,
                                            int q0, int tid, bool accum)
{
    const int tm = tid & 15, tn = tid >> 4;
    const int vl = tid >> 4, vc = tid & 15;
    for (int et = 0; et < 4; ++et) {
        float acc[4][4] = {};
        const int e0 = et * 64;
        for (int lt = 0; lt < 8; ++lt) {
            __syncthreads();
            float4 vv = *(const float4*)(V + (size_t)(lt*16 + vl) * ROWSTR + e0 + vc*4);
            *(float4*)(Bs + vl*64 + vc*4) = vv;   // straight [l][e] stage
            __syncthreads();
            #pragma unroll
            for (int kk = 0; kk < 16; ++kk) {
                float4 b = *(const float4*)(Bs + kk*64 + tn*4);
                #pragma unroll
                for (int i = 0; i < 4; ++i) {
                    float a = qk[(tm*4 + i)*129 + lt*16 + kk];
                    acc[i][0] += a*b.x; acc[i][1] += a*b.y; acc[i][2] += a*b.z; acc[i][3] += a*b.w;
                }
            }
        }
        #pragma unroll
        for (int i = 0; i < 4; ++i) {
            float* zp = Z + (size_t)(q0 + tm*4 + i) * ROWSTR + e0 + tn*4;
            float4 o; o.x = acc[i][0]; o.y = acc[i][1]; o.z = acc[i][2]; o.w = acc[i][3];
            if (accum) {
                float4 r = *(const float4*)zp;
                o.x += r.x; o.y += r.y; o.z += r.z; o.w += r.w;
            }
            *(float4*)zp = o;
        }
    }
}

// ---------------------------------------------------------------------------
// Fused attention: one block per (n,h); two 64-row slabs.
// Per slab: qk -> masked softmax (uniform row 127) -> z_P write ->
//           QE -> in-row skew remap (S[q][l]=QE[q][127-q+l], l<=q) -> z_S add.
// Zm may alias Qm: slab's Q rows fully read before its z write; slabs and
// (n,h) blocks touch disjoint row sets.
// ---------------------------------------------------------------------------
__global__ __launch_bounds__(256)
void attn_kernel(const float* __restrict__ Qm, const float* __restrict__ Km,
                 const float* __restrict__ Vm, const float* __restrict__ Ep,
                 float* __restrict__ Zm)
{
    __shared__ float qk[64 * 129];   // stride 129: column access -> (q+l)%32 banks
    __shared__ float As[16 * 64];
    __shared__ float Bs[16 * 64];
    const int tid = threadIdx.x;
    const int n = blockIdx.x >> 3, h = blockIdx.x & 7;
    const size_t base = (size_t)n * CCH * EMB + (size_t)h * EMB;
    const float* Q = Qm + base;
    const float* K = Km + base;
    const float* V = Vm + base;
    const float* E = Ep + (size_t)h * SEQL * EMB;
    float* Z = Zm + base;

    for (int ms = 0; ms < 2; ++ms) {
        const int q0 = ms * 64;

        // qk = Q_slab · K^T
        qkgemm_phase(qk, As, Bs, Q + (size_t)q0 * ROWSTR, ROWSTR, K, ROWSTR, tid);
        __syncthreads();

        // masked softmax over l>q (scale 1/16); row 127 -> uniform 1/128
        {
            const int wv = tid >> 6, lane = tid & 63;
            for (int r = 0; r < 16; ++r) {
                const int qq = wv * 16 + r;
                const int q  = q0 + qq;
                float p1, p2;
                if (q == 127) {
                    p1 = p2 = 1.0f / 128.0f;
                } else {
                    float s1 = qk[qq*129 + lane];
                    float s2 = qk[qq*129 + 64 + lane];
                    float v1 = (lane      > q) ? s1 * 0.0625f : -1e30f;
                    float v2 = (64 + lane > q) ? s2 * 0.0625f : -1e30f;
                    float m = fmaxf(v1, v2);
                    #pragma unroll
                    for (int o = 32; o > 0; o >>= 1) m = fmaxf(m, __shfl_xor(m, o));
                    float e1 = (lane      > q) ? expf(v1 - m) : 0.f;
                    float e2 = (64 + lane > q) ? expf(v2 - m) : 0.f;
                    float s = e1 + e2;
                    #pragma unroll
                    for (int o = 32; o > 0; o >>= 1) s += __shfl_xor(s, o);
                    float inv = 1.f / s;
                    p1 = e1 * inv; p2 = e2 * inv;
                }
                qk[qq*129 + lane]      = p1;
                qk[qq*129 + 64 + lane] = p2;
            }
        }
        __syncthreads();

        // z_P = P · V  (store)
        zgemm_phase(qk, Bs, V, Z, q0, tid, false);

        // QE = V_slab · Epos[h]^T  (overwrites qk; ordered by staging barriers)
        qkgemm_phase(qk, As, Bs, V + (size_t)q0 * ROWSTR, ROWSTR, E, EMB, tid);
        __syncthreads();

        // remap row q: S[q][l] = QE[q][sh+l] for l<=q (sh=127-q), else 0.
        // Two 64-reg chunks; chunk-B writes land in [0,63] so chunk-A sources
        // [64,127] are never clobbered before being read.
        if (tid < 64) {
            const int qq = tid;
            const int q  = q0 + qq;
            const int sh = 127 - q;
            float tB[64];
            #pragma unroll
            for (int j = 0; j < 64; ++j) tB[j] = qk[qq*129 + j];
            #pragma unroll
            for (int j = 0; j < 64; ++j) {
                int l = j - sh;
                if (l >= 0) qk[qq*129 + l] = tB[j];
            }
            float tA[64];
            #pragma unroll
            for (int j = 0; j < 64; ++j) tA[j] = qk[qq*129 + 64 + j];
            #pragma unroll
            for (int j = 0; j < 64; ++j) {
                int l = 64 + j - sh;
                if (l >= 0) qk[qq*129 + l] = tA[j];
            }
            for (int l = q + 1; l < 128; ++l) qk[qq*129 + l] = 0.f;
        }
        __syncthreads();

        // z_S = S · V  (accumulate into Z)
        zgemm_phase(qk, Bs, V, Z, q0, tid, true);
        __syncthreads();
    }
}

// ---------------------------------------------------------------------------
// BatchNorm over (N, E) per channel c: fold to per-row affine alpha/beta.
// ---------------------------------------------------------------------------
__global__ __launch_bounds__(256)
void bn_stats(const float* __restrict__ src, const float* __restrict__ wgt,
              const float* __restrict__ bias, float* __restrict__ alpha,
              float* __restrict__ beta)
{
    const int c = blockIdx.x;
    const int tid = threadIdx.x;
    float s = 0.f, ss = 0.f;
    const float* p = src + (size_t)c * EMB + tid;
    for (int nn = 0; nn < NB; ++nn) {
        float v = p[(size_t)nn * CCH * EMB];
        s += v; ss += v * v;
    }
    #pragma unroll
    for (int o = 32; o > 0; o >>= 1) { s += __shfl_xor(s, o); ss += __shfl_xor(ss, o); }
    __shared__ float rs[4], rss[4];
    const int wv = tid >> 6, lane = tid & 63;
    if (lane == 0) { rs[wv] = s; rss[wv] = ss; }
    __syncthreads();
    if (tid == 0) {
        float S  = rs[0] + rs[1] + rs[2] + rs[3];
        float SS = rss[0] + rss[1] + rss[2] + rss[3];
        const float invN = 1.0f / 16384.0f;
        float mean = S * invN;
        float var  = SS * invN - mean * mean;
        float a = rsqrtf(var + 1e-5f) * wgt[c];
        alpha[c] = a;
        beta[c]  = bias[c] - mean * a;
    }
}

__global__ __launch_bounds__(256)
void bn_apply(const float* __restrict__ src, const float* __restrict__ alpha,
              const float* __restrict__ beta, float* __restrict__ dst)
{
    const size_t i = (size_t)blockIdx.x * 256 + threadIdx.x;  // float4 index
    const int c = (int)((i >> 6) & 1023);
    const float a = alpha[c], b = beta[c];
    float4 v = ((const float4*)src)[i];
    v.x = v.x*a + b; v.y = v.y*a + b; v.z = v.z*a + b; v.w = v.w*a + b;
    ((float4*)dst)[i] = v;
}

// ---------------------------------------------------------------------------
extern "C" void kernel_launch(void* const* d_in, const int* in_sizes, int n_in,
                              void* d_out, int out_size, void* d_ws, size_t ws_size,
                              hipStream_t stream)
{
    const float* x  = (const float*)d_in[0];
    const float* ei = (const float*)d_in[1];
    // Only the LAST layer (i=1) affects the output (loop re-reads original x,e).
    const int L = 1;
    const float* Wv  = (const float*)d_in[2]  + (size_t)L*EMB*EMB;
    const float* bv  = (const float*)d_in[3]  + (size_t)L*EMB;
    const float* Wk  = (const float*)d_in[4]  + (size_t)L*EMB*EMB;
    const float* bk  = (const float*)d_in[5]  + (size_t)L*EMB;
    const float* Wq  = (const float*)d_in[6]  + (size_t)L*EMB*EMB;
    const float* bq  = (const float*)d_in[7]  + (size_t)L*EMB;
    const float* Ep  = (const float*)d_in[8]  + (size_t)L*NH*SEQL*EMB;
    const float* Wo  = (const float*)d_in[9]  + (size_t)L*EMB*EMB;
    const float* bo  = (const float*)d_in[10] + (size_t)L*EMB;
    const float* b2w = (const float*)d_in[11] + (size_t)L*CCH;
    const float* b2b = (const float*)d_in[12] + (size_t)L*CCH;
    const float* b3w = (const float*)d_in[13] + (size_t)L*CCH;
    const float* b3b = (const float*)d_in[14] + (size_t)L*CCH;
    const float* fW1 = (const float*)d_in[15] + (size_t)L*EMB*EMB;
    const float* fb1 = (const float*)d_in[16] + (size_t)L*EMB;
    const float* fW2 = (const float*)d_in[17] + (size_t)L*EMB*EMB;
    const float* fb2 = (const float*)d_in[18] + (size_t)L*EMB;
    const float* fcW = (const float*)d_in[19];
    const float* fcb = (const float*)d_in[20];

    float* W0   = (float*)d_ws;          // vals -> x2 -> bn3out
    float* W1   = W0 + SZ;               // keys -> r2 -> r3
    float* stat = W1 + SZ;               // alpha2,beta2,alpha3,beta3 (4x1024)
    float* OUT  = (float*)d_out;         // qrys -> z -> ff1 -> final

    dim3 blk(256);
    gemm256<0,0><<<4096, blk, 0, stream>>>(ei, Wv, bv, nullptr, W0);           // vals
    gemm256<0,0><<<4096, blk, 0, stream>>>(ei, Wk, bk, nullptr, W1);           // keys
    gemm256<0,0><<<4096, blk, 0, stream>>>(x,  Wq, bq, nullptr, OUT);          // qrys
    attn_kernel<<<512, blk, 0, stream>>>(OUT, W1, W0, Ep, OUT);                // z (in-place over qrys)
    gemm256<0,1><<<4096, blk, 0, stream>>>(OUT, Wo, bo, x, W1);                // r2 = z@Wo+bo+x
    bn_stats<<<1024, blk, 0, stream>>>(W1, b2w, b2b, stat, stat + 1024);
    bn_apply<<<16384, blk, 0, stream>>>(W1, stat, stat + 1024, W0);            // x2
    gemm256<1,0><<<4096, blk, 0, stream>>>(W0, fW1, fb1, nullptr, OUT);        // ff1 = leaky(x2@W1+b1)
    gemm256<0,1><<<4096, blk, 0, stream>>>(OUT, fW2, fb2, W0, W1);             // r3 = ff1@W2+b2+x2
    bn_stats<<<1024, blk, 0, stream>>>(W1, b3w, b3b, stat + 2048, stat + 3072);
    bn_apply<<<16384, blk, 0, stream>>>(W1, stat + 2048, stat + 3072, W0);     // bn3 out
    gemm256<0,0><<<4096, blk, 0, stream>>>(W0, fcW, fcb, nullptr, OUT);        // final @fcW+fcb
}

// Round 2
// 879.483 us; speedup vs baseline: 1.5756x; 1.5756x over previous
//
#include <hip/hip_runtime.h>
#include <math.h>

constexpr int SEQL = 128;
constexpr int NH   = 8;
constexpr int EMB  = 256;
constexpr int NB   = 64;
constexpr int CCH  = SEQL * NH;          // 1024
constexpr int ROWSTR = NH * EMB;         // 2048
constexpr size_t SZ = (size_t)NB * CCH * EMB;  // 16,777,216 floats

typedef short s16x8 __attribute__((ext_vector_type(8)));
typedef float f32x4 __attribute__((ext_vector_type(4)));

// ---- fp32 -> bf16 hi/lo split (RNE), pure bit math ----
__device__ __forceinline__ unsigned int bfr(float f) {
    unsigned int u = __float_as_uint(f);
    return (u + 0x7fffu + ((u >> 16) & 1u)) >> 16;
}
__device__ __forceinline__ void split2(float v, unsigned short& h, unsigned short& l) {
    unsigned int hb = bfr(v);
    float fh = __uint_as_float(hb << 16);
    unsigned int lb = bfr(v - fh);
    h = (unsigned short)hb; l = (unsigned short)lb;
}

// ---------------------------------------------------------------------------
// Weight pre-transpose + split: W[k][n] fp32 -> Wt_hi[n][k], Wt_lo[n][k] bf16.
// 128 blocks per matrix, 7 matrices. Coalesced u32 writes.
// ---------------------------------------------------------------------------
__global__ __launch_bounds__(256)
void wtconv(const float* __restrict__ s0, const float* __restrict__ s1,
            const float* __restrict__ s2, const float* __restrict__ s3,
            const float* __restrict__ s4, const float* __restrict__ s5,
            const float* __restrict__ s6, unsigned short* __restrict__ dst)
{
    const int mat = blockIdx.x >> 7;
    const float* s = s0;
    if (mat == 1) s = s1; else if (mat == 2) s = s2; else if (mat == 3) s = s3;
    else if (mat == 4) s = s4; else if (mat == 5) s = s5; else if (mat == 6) s = s6;
    const int o = (blockIdx.x & 127) * 512 + threadIdx.x * 2;
    const int n = o >> 8, k = o & 255;            // k even
    float v0 = s[(size_t)k * 256 + n];
    float v1 = s[(size_t)(k + 1) * 256 + n];
    unsigned short h0, l0, h1, l1;
    split2(v0, h0, l0); split2(v1, h1, l1);
    unsigned short* d = dst + (size_t)mat * 131072;
    *(unsigned int*)(d + (size_t)n * 256 + k)        = (unsigned int)h0 | ((unsigned int)h1 << 16);
    *(unsigned int*)(d + 65536 + (size_t)n * 256 + k) = (unsigned int)l0 | ((unsigned int)l1 << 16);
}

// ---------------------------------------------------------------------------
// bf16x3 MFMA GEMM: out[M,256] = op(A)[M,256] @ W[256,256] + bias (+res)(+act)
//   op(A) = al[c]*A+be[c] per channel c=row&1023 when BNIN (fused BatchNorm).
//   res term gets alr/ber affine when RESBN.
// Tile 128x128, 4 waves (each 64x64), BK=32, K-steps=8. W pre-split [n][k].
// ---------------------------------------------------------------------------
template<int BNIN, int ACT, int RES, int RESBN>
__global__ __launch_bounds__(256)
void mfma_gemm(const float* __restrict__ A,
               const unsigned short* __restrict__ WtHi,
               const unsigned short* __restrict__ WtLo,
               const float* __restrict__ bias, const float* __restrict__ res,
               const float* __restrict__ al, const float* __restrict__ be,
               const float* __restrict__ alr, const float* __restrict__ ber,
               float* __restrict__ out)
{
    __shared__ unsigned short Ahi[128 * 32];
    __shared__ unsigned short Alo[128 * 32];
    __shared__ unsigned short Bhi[128 * 32];
    __shared__ unsigned short Blo[128 * 32];

    const int tid = threadIdx.x;
    // XCD-aware swizzle (1024 % 8 == 0): each XCD gets contiguous wg range,
    // so the (m, n=0/1) pair lands on one XCD -> A-tile L2 reuse.
    const int bid = blockIdx.x;
    const int wg  = (bid & 7) * (gridDim.x >> 3) + (bid >> 3);
    const int m0 = (wg >> 1) * 128;
    const int n0 = (wg & 1) * 128;
    const int wave = tid >> 6, lane = tid & 63;
    const int wm = wave >> 1, wn = wave & 1;
    const int fr = lane & 15, fk = (lane >> 4) * 8;

    // A staging map: thread covers A[m0+arow][kt*32 + acol .. +15]
    const int arow = tid >> 1;
    const int acol = (tid & 1) * 16;
    const float* aptr = A + (size_t)(m0 + arow) * 256 + acol;
    float bnA = 1.f, bnB = 0.f;
    if (BNIN) { int c = (m0 + arow) & 1023; bnA = al[c]; bnB = be[c]; }

    f32x4 acc[4][4] = {};

    for (int kt = 0; kt < 8; ++kt) {
        const int k0 = kt * 32;
        __syncthreads();
        // ---- stage A (fp32 -> hi/lo bf16) ----
        {
            unsigned short hs[16], ls[16];
            #pragma unroll
            for (int q = 0; q < 4; ++q) {
                float4 f = *(const float4*)(aptr + k0 + q * 4);
                if (BNIN) {
                    f.x = f.x * bnA + bnB; f.y = f.y * bnA + bnB;
                    f.z = f.z * bnA + bnB; f.w = f.w * bnA + bnB;
                }
                split2(f.x, hs[q*4+0], ls[q*4+0]);
                split2(f.y, hs[q*4+1], ls[q*4+1]);
                split2(f.z, hs[q*4+2], ls[q*4+2]);
                split2(f.w, hs[q*4+3], ls[q*4+3]);
            }
            unsigned short* ah = Ahi + arow * 32 + acol;
            unsigned short* alp = Alo + arow * 32 + acol;
            *(uint4*)ah        = *(uint4*)&hs[0];
            *(uint4*)(ah + 8)  = *(uint4*)&hs[8];
            *(uint4*)alp       = *(uint4*)&ls[0];
            *(uint4*)(alp + 8) = *(uint4*)&ls[8];
        }
        // ---- stage B (pre-split bf16, straight copy of [n][k] slice) ----
        {
            #pragma unroll
            for (int half = 0; half < 2; ++half) {
                const int c = tid + half * 256;           // 16B chunk id, 512 total
                const int bn = c >> 2, bks = (c & 3) * 8;
                const size_t goff = (size_t)(n0 + bn) * 256 + k0 + bks;
                *(uint4*)((char*)Bhi + c * 16) = *(const uint4*)(WtHi + goff);
                *(uint4*)((char*)Blo + c * 16) = *(const uint4*)(WtLo + goff);
            }
        }
        __syncthreads();
        // ---- compute ----
        s16x8 ah[4], alo_[4];
        #pragma unroll
        for (int mf = 0; mf < 4; ++mf) {
            const int r = wm * 64 + mf * 16 + fr;
            ah[mf]   = *(const s16x8*)(Ahi + r * 32 + fk);
            alo_[mf] = *(const s16x8*)(Alo + r * 32 + fk);
        }
        #pragma unroll
        for (int nf = 0; nf < 4; ++nf) {
            const int cc = wn * 64 + nf * 16 + fr;
            s16x8 bh = *(const s16x8*)(Bhi + cc * 32 + fk);
            s16x8 bl = *(const s16x8*)(Blo + cc * 32 + fk);
            #pragma unroll
            for (int mf = 0; mf < 4; ++mf) {
                acc[mf][nf] = __builtin_amdgcn_mfma_f32_16x16x32_bf16(ah[mf],   bh, acc[mf][nf], 0, 0, 0);
                acc[mf][nf] = __builtin_amdgcn_mfma_f32_16x16x32_bf16(ah[mf],   bl, acc[mf][nf], 0, 0, 0);
                acc[mf][nf] = __builtin_amdgcn_mfma_f32_16x16x32_bf16(alo_[mf], bh, acc[mf][nf], 0, 0, 0);
            }
        }
    }

    // ---- epilogue: C layout col=lane&15, row=(lane>>4)*4+reg ----
    #pragma unroll
    for (int nf = 0; nf < 4; ++nf) {
        const int col = n0 + wn * 64 + nf * 16 + fr;
        const float bb = bias[col];
        #pragma unroll
        for (int mf = 0; mf < 4; ++mf) {
            #pragma unroll
            for (int r = 0; r < 4; ++r) {
                const int row = m0 + wm * 64 + mf * 16 + (lane >> 4) * 4 + r;
                float v = acc[mf][nf][r] + bb;
                if (RES) {
                    float rv = res[(size_t)row * 256 + col];
                    if (RESBN) { int c = row & 1023; rv = rv * alr[c] + ber[c]; }
                    v += rv;
                }
                if (ACT) v = v > 0.f ? v : 0.01f * v;
                out[(size_t)row * 256 + col] = v;
            }
        }
    }
}

// ---------------------------------------------------------------------------
// Attention (fp32, unchanged math). Now ONE BLOCK PER (n, h, slab): 1024 blocks.
// ---------------------------------------------------------------------------
__device__ __forceinline__ void qkgemm_phase(float* __restrict__ qk,
                                             float* __restrict__ As, float* __restrict__ Bs,
                                             const float* __restrict__ Arows, size_t astride,
                                             const float* __restrict__ Brows, size_t bstride,
                                             int tid)
{
    const int tm = tid & 15, tn = tid >> 4;
    const int lm = tid >> 2, lc = tid & 3;
    for (int lt = 0; lt < 2; ++lt) {
        float acc[4][4] = {};
        for (int et = 0; et < 16; ++et) {
            __syncthreads();
            float4 av = *(const float4*)(Arows + (size_t)lm * astride + et*16 + lc*4);
            As[(lc*4+0)*64 + lm] = av.x;
            As[(lc*4+1)*64 + lm] = av.y;
            As[(lc*4+2)*64 + lm] = av.z;
            As[(lc*4+3)*64 + lm] = av.w;
            float4 bv = *(const float4*)(Brows + (size_t)(lt*64 + lm) * bstride + et*16 + lc*4);
            Bs[(lc*4+0)*64 + lm] = bv.x;
            Bs[(lc*4+1)*64 + lm] = bv.y;
            Bs[(lc*4+2)*64 + lm] = bv.z;
            Bs[(lc*4+3)*64 + lm] = bv.w;
            __syncthreads();
            #pragma unroll
            for (int kk = 0; kk < 16; ++kk) {
                float4 a = *(const float4*)(As + kk*64 + tm*4);
                float4 b = *(const float4*)(Bs + kk*64 + tn*4);
                acc[0][0] += a.x*b.x; acc[0][1] += a.x*b.y; acc[0][2] += a.x*b.z; acc[0][3] += a.x*b.w;
                acc[1][0] += a.y*b.x; acc[1][1] += a.y*b.y; acc[1][2] += a.y*b.z; acc[1][3] += a.y*b.w;
                acc[2][0] += a.z*b.x; acc[2][1] += a.z*b.y; acc[2][2] += a.z*b.z; acc[2][3] += a.z*b.w;
                acc[3][0] += a.w*b.x; acc[3][1] += a.w*b.y; acc[3][2] += a.w*b.z; acc[3][3] += a.w*b.w;
            }
        }
        #pragma unroll
        for (int i = 0; i < 4; ++i)
            #pragma unroll
            for (int j = 0; j < 4; ++j)
                qk[(tm*4 + i)*129 + lt*64 + tn*4 + j] = acc[i][j];
    }
}

__device__ __forceinline__ void zgemm_phase(const float* __restrict__ qk,
                                            float* __restrict__ Bs,
                                            const float* __restrict__ V,
                                            float* __restrict__ Z,
                                            int q0, int tid, bool accum)
{
    const int tm = tid & 15, tn = tid >> 4;
    const int vl = tid >> 4, vc = tid & 15;
    for (int et = 0; et < 4; ++et) {
        float acc[4][4] = {};
        const int e0 = et * 64;
        for (int lt = 0; lt < 8; ++lt) {
            __syncthreads();
            float4 vv = *(const float4*)(V + (size_t)(lt*16 + vl) * ROWSTR + e0 + vc*4);
            *(float4*)(Bs + vl*64 + vc*4) = vv;
            __syncthreads();
            #pragma unroll
            for (int kk = 0; kk < 16; ++kk) {
                float4 b = *(const float4*)(Bs + kk*64 + tn*4);
                #pragma unroll
                for (int i = 0; i < 4; ++i) {
                    float a = qk[(tm*4 + i)*129 + lt*16 + kk];
                    acc[i][0] += a*b.x; acc[i][1] += a*b.y; acc[i][2] += a*b.z; acc[i][3] += a*b.w;
                }
            }
        }
        #pragma unroll
        for (int i = 0; i < 4; ++i) {
            float* zp = Z + (size_t)(q0 + tm*4 + i) * ROWSTR + e0 + tn*4;
            float4 o; o.x = acc[i][0]; o.y = acc[i][1]; o.z = acc[i][2]; o.w = acc[i][3];
            if (accum) {
                float4 r = *(const float4*)zp;
                o.x += r.x; o.y += r.y; o.z += r.z; o.w += r.w;
            }
            *(float4*)zp = o;
        }
    }
}

__global__ __launch_bounds__(256)
void attn_kernel(const float* __restrict__ Qm, const float* __restrict__ Km,
                 const float* __restrict__ Vm, const float* __restrict__ Ep,
                 float* __restrict__ Zm)
{
    __shared__ float qk[64 * 129];
    __shared__ float As[16 * 64];
    __shared__ float Bs[16 * 64];
    const int tid = threadIdx.x;
    const int n  = blockIdx.x >> 4;
    const int h  = (blockIdx.x >> 1) & 7;
    const int q0 = (blockIdx.x & 1) * 64;
    const size_t base = (size_t)n * CCH * EMB + (size_t)h * EMB;
    const float* Q = Qm + base;
    const float* K = Km + base;
    const float* V = Vm + base;
    const float* E = Ep + (size_t)h * SEQL * EMB;
    float* Z = Zm + base;

    // qk = Q_slab . K^T
    qkgemm_phase(qk, As, Bs, Q + (size_t)q0 * ROWSTR, ROWSTR, K, ROWSTR, tid);
    __syncthreads();

    // masked softmax over l>q (scale 1/16); row 127 uniform
    {
        const int wv = tid >> 6, lane = tid & 63;
        for (int r = 0; r < 16; ++r) {
            const int qq = wv * 16 + r;
            const int q  = q0 + qq;
            float p1, p2;
            if (q == 127) {
                p1 = p2 = 1.0f / 128.0f;
            } else {
                float s1 = qk[qq*129 + lane];
                float s2 = qk[qq*129 + 64 + lane];
                float v1 = (lane      > q) ? s1 * 0.0625f : -1e30f;
                float v2 = (64 + lane > q) ? s2 * 0.0625f : -1e30f;
                float m = fmaxf(v1, v2);
                #pragma unroll
                for (int o = 32; o > 0; o >>= 1) m = fmaxf(m, __shfl_xor(m, o));
                float e1 = (lane      > q) ? expf(v1 - m) : 0.f;
                float e2 = (64 + lane > q) ? expf(v2 - m) : 0.f;
                float s = e1 + e2;
                #pragma unroll
                for (int o = 32; o > 0; o >>= 1) s += __shfl_xor(s, o);
                float inv = 1.f / s;
                p1 = e1 * inv; p2 = e2 * inv;
            }
            qk[qq*129 + lane]      = p1;
            qk[qq*129 + 64 + lane] = p2;
        }
    }
    __syncthreads();

    zgemm_phase(qk, Bs, V, Z, q0, tid, false);          // z_P = P.V

    qkgemm_phase(qk, As, Bs, V + (size_t)q0 * ROWSTR, ROWSTR, E, EMB, tid);  // QE
    __syncthreads();

    // skew remap: S[q][l] = QE[q][127-q+l] for l<=q, else 0
    if (tid < 64) {
        const int qq = tid;
        const int q  = q0 + qq;
        const int sh = 127 - q;
        float tB[64];
        #pragma unroll
        for (int j = 0; j < 64; ++j) tB[j] = qk[qq*129 + j];
        #pragma unroll
        for (int j = 0; j < 64; ++j) {
            int l = j - sh;
            if (l >= 0) qk[qq*129 + l] = tB[j];
        }
        float tA[64];
        #pragma unroll
        for (int j = 0; j < 64; ++j) tA[j] = qk[qq*129 + 64 + j];
        #pragma unroll
        for (int j = 0; j < 64; ++j) {
            int l = 64 + j - sh;
            if (l >= 0) qk[qq*129 + l] = tA[j];
        }
        for (int l = q + 1; l < 128; ++l) qk[qq*129 + l] = 0.f;
    }
    __syncthreads();

    zgemm_phase(qk, Bs, V, Z, q0, tid, true);           // z += S.V
}

// ---------------------------------------------------------------------------
// BatchNorm stats -> per-channel affine (alpha, beta)
// ---------------------------------------------------------------------------
__global__ __launch_bounds__(256)
void bn_stats(const float* __restrict__ src, const float* __restrict__ wgt,
              const float* __restrict__ bias, float* __restrict__ alpha,
              float* __restrict__ beta)
{
    const int c = blockIdx.x;
    const int tid = threadIdx.x;
    float s = 0.f, ss = 0.f;
    const float* p = src + (size_t)c * EMB + tid;
    for (int nn = 0; nn < NB; ++nn) {
        float v = p[(size_t)nn * CCH * EMB];
        s += v; ss += v * v;
    }
    #pragma unroll
    for (int o = 32; o > 0; o >>= 1) { s += __shfl_xor(s, o); ss += __shfl_xor(ss, o); }
    __shared__ float rs[4], rss[4];
    const int wv = tid >> 6, lane = tid & 63;
    if (lane == 0) { rs[wv] = s; rss[wv] = ss; }
    __syncthreads();
    if (tid == 0) {
        float S  = rs[0] + rs[1] + rs[2] + rs[3];
        float SS = rss[0] + rss[1] + rss[2] + rss[3];
        const float invN = 1.0f / 16384.0f;
        float mean = S * invN;
        float var  = SS * invN - mean * mean;
        float a = rsqrtf(var + 1e-5f) * wgt[c];
        alpha[c] = a;
        beta[c]  = bias[c] - mean * a;
    }
}

// ---------------------------------------------------------------------------
extern "C" void kernel_launch(void* const* d_in, const int* in_sizes, int n_in,
                              void* d_out, int out_size, void* d_ws, size_t ws_size,
                              hipStream_t stream)
{
    const float* x  = (const float*)d_in[0];
    const float* ei = (const float*)d_in[1];
    const int L = 1;   // only the last layer affects the output
    const float* Wv  = (const float*)d_in[2]  + (size_t)L*EMB*EMB;
    const float* bv  = (const float*)d_in[3]  + (size_t)L*EMB;
    const float* Wk  = (const float*)d_in[4]  + (size_t)L*EMB*EMB;
    const float* bk  = (const float*)d_in[5]  + (size_t)L*EMB;
    const float* Wq  = (const float*)d_in[6]  + (size_t)L*EMB*EMB;
    const float* bq  = (const float*)d_in[7]  + (size_t)L*EMB;
    const float* Ep  = (const float*)d_in[8]  + (size_t)L*NH*SEQL*EMB;
    const float* Wo  = (const float*)d_in[9]  + (size_t)L*EMB*EMB;
    const float* bo  = (const float*)d_in[10] + (size_t)L*EMB;
    const float* b2w = (const float*)d_in[11] + (size_t)L*CCH;
    const float* b2b = (const float*)d_in[12] + (size_t)L*CCH;
    const float* b3w = (const float*)d_in[13] + (size_t)L*CCH;
    const float* b3b = (const float*)d_in[14] + (size_t)L*CCH;
    const float* fW1 = (const float*)d_in[15] + (size_t)L*EMB*EMB;
    const float* fb1 = (const float*)d_in[16] + (size_t)L*EMB;
    const float* fW2 = (const float*)d_in[17] + (size_t)L*EMB*EMB;
    const float* fb2 = (const float*)d_in[18] + (size_t)L*EMB;
    const float* fcW = (const float*)d_in[19];
    const float* fcb = (const float*)d_in[20];

    float* W0   = (float*)d_ws;
    float* W1   = W0 + SZ;
    float* stat = W1 + SZ;                         // 4096 floats
    unsigned short* Wt = (unsigned short*)(stat + 4096);  // 7 x 131072 ushorts
    float* OUT  = (float*)d_out;

    auto slotH = [&](int m){ return Wt + (size_t)m * 131072; };
    auto slotL = [&](int m){ return Wt + (size_t)m * 131072 + 65536; };

    dim3 blk(256);
    wtconv<<<896, blk, 0, stream>>>(Wv, Wk, Wq, Wo, fW1, fW2, fcW, Wt);

    mfma_gemm<0,0,0,0><<<1024, blk, 0, stream>>>(ei, slotH(0), slotL(0), bv,
        nullptr, nullptr, nullptr, nullptr, nullptr, W0);                        // vals
    mfma_gemm<0,0,0,0><<<1024, blk, 0, stream>>>(ei, slotH(1), slotL(1), bk,
        nullptr, nullptr, nullptr, nullptr, nullptr, W1);                        // keys
    mfma_gemm<0,0,0,0><<<1024, blk, 0, stream>>>(x,  slotH(2), slotL(2), bq,
        nullptr, nullptr, nullptr, nullptr, nullptr, OUT);                       // qrys

    attn_kernel<<<1024, blk, 0, stream>>>(OUT, W1, W0, Ep, OUT);                 // z

    mfma_gemm<0,0,1,0><<<1024, blk, 0, stream>>>(OUT, slotH(3), slotL(3), bo,
        x, nullptr, nullptr, nullptr, nullptr, W1);                              // r2 = z@Wo+bo+x
    bn_stats<<<1024, blk, 0, stream>>>(W1, b2w, b2b, stat, stat + 1024);
    mfma_gemm<1,1,0,0><<<1024, blk, 0, stream>>>(W1, slotH(4), slotL(4), fb1,
        nullptr, stat, stat + 1024, nullptr, nullptr, W0);                       // ff1 = leaky(BN2(r2)@fW1+fb1)
    mfma_gemm<0,0,1,1><<<1024, blk, 0, stream>>>(W0, slotH(5), slotL(5), fb2,
        W1, nullptr, nullptr, stat, stat + 1024, W1);                            // r3 = ff1@fW2+fb2+BN2(r2)
    bn_stats<<<1024, blk, 0, stream>>>(W1, b3w, b3b, stat + 2048, stat + 3072);
    mfma_gemm<1,0,0,0><<<1024, blk, 0, stream>>>(W1, slotH(6), slotL(6), fcb,
        nullptr, stat + 2048, stat + 3072, nullptr, nullptr, OUT);               // final
}

// Round 3
// 615.351 us; speedup vs baseline: 2.2519x; 1.4292x over previous
//
#include <hip/hip_runtime.h>
#include <math.h>

constexpr int SEQL = 128;
constexpr int NH   = 8;
constexpr int EMB  = 256;
constexpr int NB   = 64;
constexpr int CCH  = SEQL * NH;          // 1024
constexpr size_t SZ = (size_t)NB * CCH * EMB;  // 16,777,216 floats

typedef short s16x8 __attribute__((ext_vector_type(8)));
typedef float f32x4 __attribute__((ext_vector_type(4)));

// ---- fp32 -> bf16 hi/lo split (RNE) ----
__device__ __forceinline__ unsigned int bfr(float f) {
    unsigned int u = __float_as_uint(f);
    return (u + 0x7fffu + ((u >> 16) & 1u)) >> 16;
}
__device__ __forceinline__ void split2(float v, unsigned short& h, unsigned short& l) {
    unsigned int hb = bfr(v);
    float fh = __uint_as_float(hb << 16);
    unsigned int lb = bfr(v - fh);
    h = (unsigned short)hb; l = (unsigned short)lb;
}
__device__ __forceinline__ void split8(float4 a, float4 b, s16x8& h, s16x8& l) {
    unsigned short hh, ll;
    split2(a.x, hh, ll); h[0] = (short)hh; l[0] = (short)ll;
    split2(a.y, hh, ll); h[1] = (short)hh; l[1] = (short)ll;
    split2(a.z, hh, ll); h[2] = (short)hh; l[2] = (short)ll;
    split2(a.w, hh, ll); h[3] = (short)hh; l[3] = (short)ll;
    split2(b.x, hh, ll); h[4] = (short)hh; l[4] = (short)ll;
    split2(b.y, hh, ll); h[5] = (short)hh; l[5] = (short)ll;
    split2(b.z, hh, ll); h[6] = (short)hh; l[6] = (short)ll;
    split2(b.w, hh, ll); h[7] = (short)hh; l[7] = (short)ll;
}

// ---------------------------------------------------------------------------
// Weight pre-transpose + split: W[k][n] fp32 -> Wt_hi[n][k], Wt_lo[n][k] bf16.
// ---------------------------------------------------------------------------
__global__ __launch_bounds__(256)
void wtconv(const float* __restrict__ s0, const float* __restrict__ s1,
            const float* __restrict__ s2, const float* __restrict__ s3,
            const float* __restrict__ s4, const float* __restrict__ s5,
            const float* __restrict__ s6, unsigned short* __restrict__ dst)
{
    const int mat = blockIdx.x >> 7;
    const float* s = s0;
    if (mat == 1) s = s1; else if (mat == 2) s = s2; else if (mat == 3) s = s3;
    else if (mat == 4) s = s4; else if (mat == 5) s = s5; else if (mat == 6) s = s6;
    const int o = (blockIdx.x & 127) * 512 + threadIdx.x * 2;
    const int n = o >> 8, k = o & 255;
    float v0 = s[(size_t)k * 256 + n];
    float v1 = s[(size_t)(k + 1) * 256 + n];
    unsigned short h0, l0, h1, l1;
    split2(v0, h0, l0); split2(v1, h1, l1);
    unsigned short* d = dst + (size_t)mat * 131072;
    *(unsigned int*)(d + (size_t)n * 256 + k)        = (unsigned int)h0 | ((unsigned int)h1 << 16);
    *(unsigned int*)(d + 65536 + (size_t)n * 256 + k) = (unsigned int)l0 | ((unsigned int)l1 << 16);
}

// ---------------------------------------------------------------------------
// Epos (layer slice) fp32 -> bf16 hi
// ---------------------------------------------------------------------------
__global__ __launch_bounds__(256)
void prep_eh(const float* __restrict__ E, unsigned short* __restrict__ eh)
{
    const int i = (blockIdx.x * 256 + threadIdx.x) * 4;   // 262144 elements total
    float4 f = *(const float4*)(E + i);
    unsigned int p0 = bfr(f.x) | (bfr(f.y) << 16);
    unsigned int p1 = bfr(f.z) | (bfr(f.w) << 16);
    ((unsigned int*)eh)[(i >> 1)]     = p0;
    ((unsigned int*)eh)[(i >> 1) + 1] = p1;
}

// ---------------------------------------------------------------------------
// bf16x3 MFMA GEMM: out[M,256] = op(A)[M,256] @ W[256,256] + bias (+res)(+act)
// OUT16: write bf16-hi (RNE) to o16 instead of fp32 out.
// ---------------------------------------------------------------------------
template<int BNIN, int ACT, int RES, int RESBN, int OUT16>
__global__ __launch_bounds__(256)
void mfma_gemm(const float* __restrict__ A,
               const unsigned short* __restrict__ WtHi,
               const unsigned short* __restrict__ WtLo,
               const float* __restrict__ bias, const float* __restrict__ res,
               const float* __restrict__ al, const float* __restrict__ be,
               const float* __restrict__ alr, const float* __restrict__ ber,
               float* __restrict__ out, unsigned short* __restrict__ o16)
{
    __shared__ unsigned short Ahi[128 * 32];
    __shared__ unsigned short Alo[128 * 32];
    __shared__ unsigned short Bhi[128 * 32];
    __shared__ unsigned short Blo[128 * 32];

    const int tid = threadIdx.x;
    const int bid = blockIdx.x;
    const int wg  = (bid & 7) * (gridDim.x >> 3) + (bid >> 3);
    const int m0 = (wg >> 1) * 128;
    const int n0 = (wg & 1) * 128;
    const int wave = tid >> 6, lane = tid & 63;
    const int wm = wave >> 1, wn = wave & 1;
    const int fr = lane & 15, fk = (lane >> 4) * 8;

    const int arow = tid >> 1;
    const int acol = (tid & 1) * 16;
    const float* aptr = A + (size_t)(m0 + arow) * 256 + acol;
    float bnA = 1.f, bnB = 0.f;
    if (BNIN) { int c = (m0 + arow) & 1023; bnA = al[c]; bnB = be[c]; }

    f32x4 acc[4][4] = {};

    for (int kt = 0; kt < 8; ++kt) {
        const int k0 = kt * 32;
        __syncthreads();
        {
            unsigned short hs[16], ls[16];
            #pragma unroll
            for (int q = 0; q < 4; ++q) {
                float4 f = *(const float4*)(aptr + k0 + q * 4);
                if (BNIN) {
                    f.x = f.x * bnA + bnB; f.y = f.y * bnA + bnB;
                    f.z = f.z * bnA + bnB; f.w = f.w * bnA + bnB;
                }
                split2(f.x, hs[q*4+0], ls[q*4+0]);
                split2(f.y, hs[q*4+1], ls[q*4+1]);
                split2(f.z, hs[q*4+2], ls[q*4+2]);
                split2(f.w, hs[q*4+3], ls[q*4+3]);
            }
            unsigned short* ah = Ahi + arow * 32 + acol;
            unsigned short* alp = Alo + arow * 32 + acol;
            *(uint4*)ah        = *(uint4*)&hs[0];
            *(uint4*)(ah + 8)  = *(uint4*)&hs[8];
            *(uint4*)alp       = *(uint4*)&ls[0];
            *(uint4*)(alp + 8) = *(uint4*)&ls[8];
        }
        {
            #pragma unroll
            for (int half = 0; half < 2; ++half) {
                const int c = tid + half * 256;
                const int bn = c >> 2, bks = (c & 3) * 8;
                const size_t goff = (size_t)(n0 + bn) * 256 + k0 + bks;
                *(uint4*)((char*)Bhi + c * 16) = *(const uint4*)(WtHi + goff);
                *(uint4*)((char*)Blo + c * 16) = *(const uint4*)(WtLo + goff);
            }
        }
        __syncthreads();
        s16x8 ah[4], alo_[4];
        #pragma unroll
        for (int mf = 0; mf < 4; ++mf) {
            const int r = wm * 64 + mf * 16 + fr;
            ah[mf]   = *(const s16x8*)(Ahi + r * 32 + fk);
            alo_[mf] = *(const s16x8*)(Alo + r * 32 + fk);
        }
        #pragma unroll
        for (int nf = 0; nf < 4; ++nf) {
            const int cc = wn * 64 + nf * 16 + fr;
            s16x8 bh = *(const s16x8*)(Bhi + cc * 32 + fk);
            s16x8 bl = *(const s16x8*)(Blo + cc * 32 + fk);
            #pragma unroll
            for (int mf = 0; mf < 4; ++mf) {
                acc[mf][nf] = __builtin_amdgcn_mfma_f32_16x16x32_bf16(ah[mf],   bh, acc[mf][nf], 0, 0, 0);
                acc[mf][nf] = __builtin_amdgcn_mfma_f32_16x16x32_bf16(ah[mf],   bl, acc[mf][nf], 0, 0, 0);
                acc[mf][nf] = __builtin_amdgcn_mfma_f32_16x16x32_bf16(alo_[mf], bh, acc[mf][nf], 0, 0, 0);
            }
        }
    }

    #pragma unroll
    for (int nf = 0; nf < 4; ++nf) {
        const int col = n0 + wn * 64 + nf * 16 + fr;
        const float bb = bias[col];
        #pragma unroll
        for (int mf = 0; mf < 4; ++mf) {
            #pragma unroll
            for (int r = 0; r < 4; ++r) {
                const int row = m0 + wm * 64 + mf * 16 + (lane >> 4) * 4 + r;
                float v = acc[mf][nf][r] + bb;
                if (RES) {
                    float rv = res[(size_t)row * 256 + col];
                    if (RESBN) { int c = row & 1023; rv = rv * alr[c] + ber[c]; }
                    v += rv;
                }
                if (ACT) v = v > 0.f ? v : 0.01f * v;
                if (OUT16) o16[(size_t)row * 256 + col] = (unsigned short)bfr(v);
                else       out[(size_t)row * 256 + col] = v;
            }
        }
    }
}

// ---------------------------------------------------------------------------
// MFMA attention. Block = (n, h, slab of 64 q-rows); 4 waves, each 16 q-rows.
//  Phase 1: S1 = Q.K^T (A=Q fp32 split x2, B=Kh bf16 direct-from-global)
//           -> in-register masked softmax (row 127 uniform falls out) -> P
//           -> att LDS (hi/lo bf16). P covers l>q.
//  Phase 2: QE = V.E^T (A=V fp32 split x2, B=Eh bf16) -> skew write
//           S[q][j-127+q]=QE[q][j] covers l<=q (disjoint; row127 adds 1/128).
//  Phase 3: Z = att.V via Vt (V^T staged in LDS bf16, two 64-l halves).
// att rows are wave-private (written and read by the same wave).
// Zm aliases Qm: all Q reads (phase 1) precede Z writes; blocks own disjoint rows.
// ---------------------------------------------------------------------------
__global__ __launch_bounds__(256)
void attn_mfma(const float* __restrict__ Qm, const unsigned short* __restrict__ Kh,
               const float* __restrict__ Vm, const unsigned short* __restrict__ Eh,
               float* __restrict__ Zm)
{
    __shared__ unsigned short att_h[64 * 136];
    __shared__ unsigned short att_l[64 * 136];
    __shared__ unsigned short Vt[256 * 72];

    const int tid = threadIdx.x;
    const int n  = blockIdx.x >> 4;
    const int h  = (blockIdx.x >> 1) & 7;
    const int q0 = (blockIdx.x & 1) * 64;
    const int w = tid >> 6, lane = tid & 63;
    const int fr = lane & 15, g = lane >> 4;
    const int fk = g * 8;

    const size_t nb = (size_t)n * 1024 + h;      // row(s) = nb + s*8, scaled by 256
    #define GROW(s) ((nb + (size_t)(s) * 8) * 256)

    const int qa = q0 + 16 * w + fr;             // A-fragment row (this wave's tile)

    // ---------------- Phase 1: QK + softmax -> P ----------------
    f32x4 acc[8];
    #pragma unroll
    for (int nf = 0; nf < 8; ++nf) acc[nf] = (f32x4){0.f, 0.f, 0.f, 0.f};

    for (int kt = 0; kt < 8; ++kt) {
        const float* qp = Qm + GROW(qa) + kt * 32 + fk;
        float4 f0 = *(const float4*)qp;
        float4 f1 = *(const float4*)(qp + 4);
        s16x8 ah, al_;
        split8(f0, f1, ah, al_);
        #pragma unroll
        for (int nf = 0; nf < 8; ++nf) {
            const int l = nf * 16 + fr;
            s16x8 bh = *(const s16x8*)(Kh + GROW(l) + kt * 32 + fk);
            acc[nf] = __builtin_amdgcn_mfma_f32_16x16x32_bf16(ah,  bh, acc[nf], 0, 0, 0);
            acc[nf] = __builtin_amdgcn_mfma_f32_16x16x32_bf16(al_, bh, acc[nf], 0, 0, 0);
        }
    }

    #pragma unroll
    for (int r = 0; r < 4; ++r) {
        const int q    = q0 + 16 * w + g * 4 + r;
        const int qloc = 16 * w + g * 4 + r;
        float v[8];
        float m = -1e30f;
        #pragma unroll
        for (int nf = 0; nf < 8; ++nf) {
            const int l = nf * 16 + fr;
            v[nf] = (l > q) ? acc[nf][r] * 0.0625f : -1e30f;
            m = fmaxf(m, v[nf]);
        }
        #pragma unroll
        for (int o = 8; o > 0; o >>= 1) m = fmaxf(m, __shfl_xor(m, o));
        float s = 0.f;
        #pragma unroll
        for (int nf = 0; nf < 8; ++nf) { v[nf] = expf(v[nf] - m); s += v[nf]; }
        #pragma unroll
        for (int o = 8; o > 0; o >>= 1) s += __shfl_xor(s, o);
        const float inv = 1.f / s;
        #pragma unroll
        for (int nf = 0; nf < 8; ++nf) {
            unsigned short hh, ll;
            split2(v[nf] * inv, hh, ll);
            att_h[qloc * 136 + nf * 16 + fr] = hh;
            att_l[qloc * 136 + nf * 16 + fr] = ll;
        }
    }

    // ---------------- Phase 2: QE + skew -> S ----------------
    #pragma unroll
    for (int nf = 0; nf < 8; ++nf) acc[nf] = (f32x4){0.f, 0.f, 0.f, 0.f};

    for (int kt = 0; kt < 8; ++kt) {
        const float* vp = Vm + GROW(qa) + kt * 32 + fk;
        float4 f0 = *(const float4*)vp;
        float4 f1 = *(const float4*)(vp + 4);
        s16x8 ah, al_;
        split8(f0, f1, ah, al_);
        #pragma unroll
        for (int nf = 0; nf < 8; ++nf) {
            const int j = nf * 16 + fr;
            s16x8 bh = *(const s16x8*)(Eh + ((size_t)(h * 128 + j)) * 256 + kt * 32 + fk);
            acc[nf] = __builtin_amdgcn_mfma_f32_16x16x32_bf16(ah,  bh, acc[nf], 0, 0, 0);
            acc[nf] = __builtin_amdgcn_mfma_f32_16x16x32_bf16(al_, bh, acc[nf], 0, 0, 0);
        }
    }

    #pragma unroll
    for (int r = 0; r < 4; ++r) {
        const int q    = q0 + 16 * w + g * 4 + r;
        const int qloc = 16 * w + g * 4 + r;
        #pragma unroll
        for (int nf = 0; nf < 8; ++nf) {
            const int j  = nf * 16 + fr;
            const int lt = j - 127 + q;
            float sv = acc[nf][r];
            if (q == 127) sv += 0.0078125f;           // + uniform P row
            if (lt >= 0) {
                unsigned short hh, ll;
                split2(sv, hh, ll);
                att_h[qloc * 136 + lt] = hh;
                att_l[qloc * 136 + lt] = ll;
            }
        }
    }

    // ---------------- Phase 3: Z = att . V ----------------
    f32x4 az[16];
    #pragma unroll
    for (int nf = 0; nf < 16; ++nf) az[nf] = (f32x4){0.f, 0.f, 0.f, 0.f};

    const int lrow = tid & 63, ec = tid >> 6;
    for (int half = 0; half < 2; ++half) {
        __syncthreads();                               // prior Vt readers done
        {
            const float* vsrc = Vm + GROW(half * 64 + lrow) + ec * 64;
            #pragma unroll
            for (int c = 0; c < 8; ++c) {
                float4 f0 = *(const float4*)(vsrc + c * 8);
                float4 f1 = *(const float4*)(vsrc + c * 8 + 4);
                const int e = ec * 64 + c * 8;
                Vt[(e + 0) * 72 + lrow] = (unsigned short)bfr(f0.x);
                Vt[(e + 1) * 72 + lrow] = (unsigned short)bfr(f0.y);
                Vt[(e + 2) * 72 + lrow] = (unsigned short)bfr(f0.z);
                Vt[(e + 3) * 72 + lrow] = (unsigned short)bfr(f0.w);
                Vt[(e + 4) * 72 + lrow] = (unsigned short)bfr(f1.x);
                Vt[(e + 5) * 72 + lrow] = (unsigned short)bfr(f1.y);
                Vt[(e + 6) * 72 + lrow] = (unsigned short)bfr(f1.z);
                Vt[(e + 7) * 72 + lrow] = (unsigned short)bfr(f1.w);
            }
        }
        __syncthreads();
        #pragma unroll
        for (int kt = 0; kt < 2; ++kt) {
            const int lg = half * 64 + kt * 32 + fk;   // global l for att cols
            s16x8 ah  = *(const s16x8*)(att_h + (16 * w + fr) * 136 + lg);
            s16x8 al_ = *(const s16x8*)(att_l + (16 * w + fr) * 136 + lg);
            #pragma unroll
            for (int nf = 0; nf < 16; ++nf) {
                s16x8 bh = *(const s16x8*)(Vt + (nf * 16 + fr) * 72 + kt * 32 + fk);
                az[nf] = __builtin_amdgcn_mfma_f32_16x16x32_bf16(ah,  bh, az[nf], 0, 0, 0);
                az[nf] = __builtin_amdgcn_mfma_f32_16x16x32_bf16(al_, bh, az[nf], 0, 0, 0);
            }
        }
    }

    #pragma unroll
    for (int r = 0; r < 4; ++r) {
        const int q = q0 + 16 * w + g * 4 + r;
        float* zp = Zm + GROW(q);
        #pragma unroll
        for (int nf = 0; nf < 16; ++nf) zp[nf * 16 + fr] = az[nf][r];
    }
    #undef GROW
}

// ---------------------------------------------------------------------------
// BatchNorm stats -> per-channel affine (alpha, beta)
// ---------------------------------------------------------------------------
__global__ __launch_bounds__(256)
void bn_stats(const float* __restrict__ src, const float* __restrict__ wgt,
              const float* __restrict__ bias, float* __restrict__ alpha,
              float* __restrict__ beta)
{
    const int c = blockIdx.x;
    const int tid = threadIdx.x;
    float s = 0.f, ss = 0.f;
    const float* p = src + (size_t)c * EMB + tid;
    for (int nn = 0; nn < NB; ++nn) {
        float v = p[(size_t)nn * CCH * EMB];
        s += v; ss += v * v;
    }
    #pragma unroll
    for (int o = 32; o > 0; o >>= 1) { s += __shfl_xor(s, o); ss += __shfl_xor(ss, o); }
    __shared__ float rs[4], rss[4];
    const int wv = tid >> 6, lane = tid & 63;
    if (lane == 0) { rs[wv] = s; rss[wv] = ss; }
    __syncthreads();
    if (tid == 0) {
        float S  = rs[0] + rs[1] + rs[2] + rs[3];
        float SS = rss[0] + rss[1] + rss[2] + rss[3];
        const float invN = 1.0f / 16384.0f;
        float mean = S * invN;
        float var  = SS * invN - mean * mean;
        float a = rsqrtf(var + 1e-5f) * wgt[c];
        alpha[c] = a;
        beta[c]  = bias[c] - mean * a;
    }
}

// ---------------------------------------------------------------------------
extern "C" void kernel_launch(void* const* d_in, const int* in_sizes, int n_in,
                              void* d_out, int out_size, void* d_ws, size_t ws_size,
                              hipStream_t stream)
{
    const float* x  = (const float*)d_in[0];
    const float* ei = (const float*)d_in[1];
    const int L = 1;   // only the last layer affects the output
    const float* Wv  = (const float*)d_in[2]  + (size_t)L*EMB*EMB;
    const float* bv  = (const float*)d_in[3]  + (size_t)L*EMB;
    const float* Wk  = (const float*)d_in[4]  + (size_t)L*EMB*EMB;
    const float* bk  = (const float*)d_in[5]  + (size_t)L*EMB;
    const float* Wq  = (const float*)d_in[6]  + (size_t)L*EMB*EMB;
    const float* bq  = (const float*)d_in[7]  + (size_t)L*EMB;
    const float* Ep  = (const float*)d_in[8]  + (size_t)L*NH*SEQL*EMB;
    const float* Wo  = (const float*)d_in[9]  + (size_t)L*EMB*EMB;
    const float* bo  = (const float*)d_in[10] + (size_t)L*EMB;
    const float* b2w = (const float*)d_in[11] + (size_t)L*CCH;
    const float* b2b = (const float*)d_in[12] + (size_t)L*CCH;
    const float* b3w = (const float*)d_in[13] + (size_t)L*CCH;
    const float* b3b = (const float*)d_in[14] + (size_t)L*CCH;
    const float* fW1 = (const float*)d_in[15] + (size_t)L*EMB*EMB;
    const float* fb1 = (const float*)d_in[16] + (size_t)L*EMB;
    const float* fW2 = (const float*)d_in[17] + (size_t)L*EMB*EMB;
    const float* fb2 = (const float*)d_in[18] + (size_t)L*EMB;
    const float* fcW = (const float*)d_in[19];
    const float* fcb = (const float*)d_in[20];

    float* W0   = (float*)d_ws;                          // vals(fp32) -> ff1 -> bn-free
    float* W1   = W0 + SZ;                               // [kh bf16 alias] -> r2 -> r3
    float* stat = W1 + SZ;                               // 4096 floats
    unsigned short* Wt = (unsigned short*)(stat + 4096); // 7 x 131072 u16
    unsigned short* ehb = Wt + (size_t)7 * 131072;       // 262144 u16
    unsigned short* kh  = (unsigned short*)W1;           // K bf16-hi (dead until r2)
    float* OUT  = (float*)d_out;                         // qrys -> z -> final

    auto slotH = [&](int m){ return Wt + (size_t)m * 131072; };
    auto slotL = [&](int m){ return Wt + (size_t)m * 131072 + 65536; };

    dim3 blk(256);
    wtconv<<<896, blk, 0, stream>>>(Wv, Wk, Wq, Wo, fW1, fW2, fcW, Wt);
    prep_eh<<<256, blk, 0, stream>>>(Ep, ehb);

    mfma_gemm<0,0,0,0,0><<<1024, blk, 0, stream>>>(ei, slotH(0), slotL(0), bv,
        nullptr, nullptr, nullptr, nullptr, nullptr, W0, nullptr);               // vals (fp32)
    mfma_gemm<0,0,0,0,1><<<1024, blk, 0, stream>>>(ei, slotH(1), slotL(1), bk,
        nullptr, nullptr, nullptr, nullptr, nullptr, nullptr, kh);               // keys (bf16-hi)
    mfma_gemm<0,0,0,0,0><<<1024, blk, 0, stream>>>(x,  slotH(2), slotL(2), bq,
        nullptr, nullptr, nullptr, nullptr, nullptr, OUT, nullptr);              // qrys (fp32)

    attn_mfma<<<1024, blk, 0, stream>>>(OUT, kh, W0, ehb, OUT);                  // z (in-place)

    mfma_gemm<0,0,1,0,0><<<1024, blk, 0, stream>>>(OUT, slotH(3), slotL(3), bo,
        x, nullptr, nullptr, nullptr, nullptr, W1, nullptr);                     // r2 = z@Wo+bo+x
    bn_stats<<<1024, blk, 0, stream>>>(W1, b2w, b2b, stat, stat + 1024);
    mfma_gemm<1,1,0,0,0><<<1024, blk, 0, stream>>>(W1, slotH(4), slotL(4), fb1,
        nullptr, stat, stat + 1024, nullptr, nullptr, W0, nullptr);              // ff1
    mfma_gemm<0,0,1,1,0><<<1024, blk, 0, stream>>>(W0, slotH(5), slotL(5), fb2,
        W1, nullptr, nullptr, stat, stat + 1024, W1, nullptr);                   // r3
    bn_stats<<<1024, blk, 0, stream>>>(W1, b3w, b3b, stat + 2048, stat + 3072);
    mfma_gemm<1,0,0,0,0><<<1024, blk, 0, stream>>>(W1, slotH(6), slotL(6), fcb,
        nullptr, stat + 2048, stat + 3072, nullptr, nullptr, OUT, nullptr);      // final
}